// Round 10
// baseline (6337.122 us; speedup 1.0000x reference)
//
#include <hip/hip_runtime.h>

#define NN 20000
#define NE 160000
#define HD 128

__device__ __forceinline__ float bf2f(unsigned short u){
  union { unsigned int i; float f; } v; v.i = ((unsigned int)u) << 16; return v.f;
}
__device__ __forceinline__ unsigned short f2bf(float f){
  union { float f; unsigned int i; } v; v.f = f;
  unsigned int r = v.i + 0x7fffu + ((v.i >> 16) & 1u);
  return (unsigned short)(r >> 16);
}

__global__ void sentinel_kernel(float* out, float code){
  if (threadIdx.x < 32) out[threadIdx.x] = code;
}

// ---------------- init ----------------
__global__ __launch_bounds__(128) void init_small(
    float* g, float* cbe, float* cbv, float* xvs, float* xes,
    const float* Eb1_0, const float* Vb1_0)
{
  int t = threadIdx.x;
  g[t] = 0.f; xvs[t] = 0.f; xes[t] = 0.f;
  cbe[t] = Eb1_0[t]; cbv[t] = Vb1_0[t];
}

__global__ __launch_bounds__(256) void zero_aggr(float* aggr){
  size_t i = (size_t)blockIdx.x * 256 + threadIdx.x;
  aggr[i] = 0.f;
}

// ---------------- node encoder: 32 rows/block, fp32 ----------------
__global__ __launch_bounds__(128) void enc_node(
    const float* x, const float* W1, const float* b1,
    const float* W2, const float* b2, const float* gl, const float* bl,
    float* xvf)
{
  __shared__ float xin[32*12];
  __shared__ float hb[32*128];
  __shared__ float ob[32*128];
  int t = threadIdx.x, r0 = blockIdx.x * 32;
  for (int j = t; j < 32*12; j += 128){
    int r = j / 12, k = j % 12;
    xin[j] = x[(size_t)(r0 + r)*12 + k];
  }
  __syncthreads();
  float acc[32];
  {
    float bb = b1[t];
    #pragma unroll
    for (int r = 0; r < 32; ++r) acc[r] = bb;
    for (int k = 0; k < 12; ++k){
      float w = W1[k*HD + t];
      #pragma unroll
      for (int r = 0; r < 32; ++r) acc[r] += xin[r*12 + k] * w;
    }
    #pragma unroll
    for (int r = 0; r < 32; ++r) hb[r*128 + t] = fmaxf(acc[r], 0.f);
  }
  __syncthreads();
  {
    float bb = b2[t];
    #pragma unroll
    for (int r = 0; r < 32; ++r) acc[r] = bb;
    for (int k = 0; k < HD; ++k){
      float w = W2[k*HD + t];
      #pragma unroll
      for (int r = 0; r < 32; ++r) acc[r] += hb[r*128 + k] * w;
    }
    #pragma unroll
    for (int r = 0; r < 32; ++r) ob[r*128 + t] = acc[r];
  }
  __syncthreads();
  int row = t >> 2, sub = t & 3;
  float s = 0.f;
  for (int j = 0; j < 32; ++j) s += ob[row*128 + sub*32 + j];
  s += __shfl_xor(s, 1); s += __shfl_xor(s, 2);
  float mean = s * 0.0078125f;
  float v = 0.f;
  for (int j = 0; j < 32; ++j){ float d = ob[row*128 + sub*32 + j] - mean; v += d*d; }
  v += __shfl_xor(v, 1); v += __shfl_xor(v, 2);
  float rs = rsqrtf(v * 0.0078125f + 1e-5f);
  int rg = r0 + row;
  for (int j = 0; j < 32; ++j){
    int c = sub*32 + j;
    xvf[(size_t)rg*HD + c] = (ob[row*128 + c] - mean)*rs*gl[c] + bl[c];
  }
}

// ---------------- edge encoder: 32 rows/block, K=4 ----------------
__global__ __launch_bounds__(128) void enc_edge(
    const float* ea, const float* W1, const float* b1,
    const float* W2, const float* b2, const float* gl, const float* bl,
    unsigned short* xeb)
{
  __shared__ float xin[32*4];
  __shared__ float hb[32*128];
  __shared__ float ob[32*128];
  int t = threadIdx.x, r0 = blockIdx.x * 32;
  if (t < 128){
    int r = t >> 2, k = t & 3;
    xin[t] = ea[(size_t)(r0 + r)*4 + k];
  }
  __syncthreads();
  float acc[32];
  {
    float bb = b1[t];
    #pragma unroll
    for (int r = 0; r < 32; ++r) acc[r] = bb;
    #pragma unroll
    for (int k = 0; k < 4; ++k){
      float w = W1[k*HD + t];
      #pragma unroll
      for (int r = 0; r < 32; ++r) acc[r] += xin[r*4 + k] * w;
    }
    #pragma unroll
    for (int r = 0; r < 32; ++r) hb[r*128 + t] = fmaxf(acc[r], 0.f);
  }
  __syncthreads();
  {
    float bb = b2[t];
    #pragma unroll
    for (int r = 0; r < 32; ++r) acc[r] = bb;
    for (int k = 0; k < HD; ++k){
      float w = W2[k*HD + t];
      #pragma unroll
      for (int r = 0; r < 32; ++r) acc[r] += hb[r*128 + k] * w;
    }
    #pragma unroll
    for (int r = 0; r < 32; ++r) ob[r*128 + t] = acc[r];
  }
  __syncthreads();
  int row = t >> 2, sub = t & 3;
  float s = 0.f;
  for (int j = 0; j < 32; ++j) s += ob[row*128 + sub*32 + j];
  s += __shfl_xor(s, 1); s += __shfl_xor(s, 2);
  float mean = s * 0.0078125f;
  float v = 0.f;
  for (int j = 0; j < 32; ++j){ float d = ob[row*128 + sub*32 + j] - mean; v += d*d; }
  v += __shfl_xor(v, 1); v += __shfl_xor(v, 2);
  float rs = rsqrtf(v * 0.0078125f + 1e-5f);
  int rg = r0 + row;
  for (int j = 0; j < 32; ++j){
    int c = sub*32 + j;
    float o = (ob[row*128 + c] - mean)*rs*gl[c] + bl[c];
    xeb[(size_t)rg*HD + c] = f2bf(o);
  }
}

// ---------------- edge update: 16 edges/block ----------------
__global__ __launch_bounds__(128) void edge_kernel(
    unsigned short* xeb, const int* eidx, const float* xvf, const float* cbe,
    const float* EW1, const float* EW2, const float* Eb2,
    const float* Eg, const float* Ebt,
    float* aggr, float* xes)
{
  __shared__ float xvS[16*128], xvR[16*128], xeS[16*128], hb[16*128], ob[16*128];
  __shared__ int sidx[16], ridx[16];
  int t = threadIdx.x, e0 = blockIdx.x * 16;
  if (t < 16){ sidx[t] = eidx[e0 + t]; ridx[t] = eidx[NE + e0 + t]; }
  __syncthreads();
  #pragma unroll
  for (int r = 0; r < 16; ++r){
    xvS[r*128 + t] = xvf[(size_t)sidx[r]*HD + t];
    xvR[r*128 + t] = xvf[(size_t)ridx[r]*HD + t];
    xeS[r*128 + t] = bf2f(xeb[(size_t)(e0 + r)*HD + t]);
  }
  __syncthreads();
  float acc[16];
  {
    float bb = cbe[t];
    #pragma unroll
    for (int r = 0; r < 16; ++r) acc[r] = bb;
    for (int k = 0; k < HD; ++k){
      float w = EW1[(size_t)k*HD + t];
      #pragma unroll
      for (int r = 0; r < 16; ++r) acc[r] += xvS[r*128 + k] * w;
    }
    for (int k = 0; k < HD; ++k){
      float w = EW1[(size_t)(128 + k)*HD + t];
      #pragma unroll
      for (int r = 0; r < 16; ++r) acc[r] += xvR[r*128 + k] * w;
    }
    for (int k = 0; k < HD; ++k){
      float w = EW1[(size_t)(256 + k)*HD + t];
      #pragma unroll
      for (int r = 0; r < 16; ++r) acc[r] += xeS[r*128 + k] * w;
    }
    #pragma unroll
    for (int r = 0; r < 16; ++r) hb[r*128 + t] = fmaxf(acc[r], 0.f);
  }
  __syncthreads();
  {
    float bb = Eb2[t];
    #pragma unroll
    for (int r = 0; r < 16; ++r) acc[r] = bb;
    for (int k = 0; k < HD; ++k){
      float w = EW2[(size_t)k*HD + t];
      #pragma unroll
      for (int r = 0; r < 16; ++r) acc[r] += hb[r*128 + k] * w;
    }
    #pragma unroll
    for (int r = 0; r < 16; ++r) ob[r*128 + t] = acc[r];
  }
  __syncthreads();
  int row = t >> 3, sub = t & 7;
  float s = 0.f;
  for (int j = 0; j < 16; ++j) s += ob[row*128 + sub*16 + j];
  s += __shfl_xor(s, 1); s += __shfl_xor(s, 2); s += __shfl_xor(s, 4);
  float mean = s * 0.0078125f;
  float v = 0.f;
  for (int j = 0; j < 16; ++j){ float d = ob[row*128 + sub*16 + j] - mean; v += d*d; }
  v += __shfl_xor(v, 1); v += __shfl_xor(v, 2); v += __shfl_xor(v, 4);
  float rs = rsqrtf(v * 0.0078125f + 1e-5f);
  int rnode = ridx[row];
  for (int j = 0; j < 16; ++j){
    int c = sub*16 + j;
    float o = (ob[row*128 + c] - mean)*rs*Eg[c] + Ebt[c];
    float nv = xeS[row*128 + c] + o;
    xeb[(size_t)(e0 + row)*HD + c] = f2bf(nv);
    atomicAdd(&aggr[(size_t)rnode*HD + c], nv);
    ob[row*128 + c] = nv;
  }
  __syncthreads();
  float cs = 0.f;
  #pragma unroll
  for (int r = 0; r < 16; ++r) cs += ob[r*128 + t];
  atomicAdd(&xes[t], cs);
}

// ---------------- node update: 32 nodes/block ----------------
__global__ __launch_bounds__(128) void node_kernel(
    float* xvf, const float* aggr, const float* cbv,
    const float* VW1, const float* VW2, const float* Vb2,
    const float* Vg, const float* Vbt,
    float* xvs)
{
  __shared__ float xv[32*128], ag[32*128], ob[32*128];
  int t = threadIdx.x, r0 = blockIdx.x * 32;
  #pragma unroll
  for (int r = 0; r < 32; ++r){
    xv[r*128 + t] = xvf[(size_t)(r0 + r)*HD + t];
    ag[r*128 + t] = aggr[(size_t)(r0 + r)*HD + t];
  }
  __syncthreads();
  float acc[32];
  {
    float bb = cbv[t];
    #pragma unroll
    for (int r = 0; r < 32; ++r) acc[r] = bb;
    for (int k = 0; k < HD; ++k){
      float w = VW1[(size_t)k*HD + t];
      #pragma unroll
      for (int r = 0; r < 32; ++r) acc[r] += xv[r*128 + k] * w;
    }
    for (int k = 0; k < HD; ++k){
      float w = VW1[(size_t)(128 + k)*HD + t];
      #pragma unroll
      for (int r = 0; r < 32; ++r) acc[r] += ag[r*128 + k] * w;
    }
  }
  __syncthreads();
  #pragma unroll
  for (int r = 0; r < 32; ++r) ag[r*128 + t] = fmaxf(acc[r], 0.f);
  __syncthreads();
  {
    float bb = Vb2[t];
    #pragma unroll
    for (int r = 0; r < 32; ++r) acc[r] = bb;
    for (int k = 0; k < HD; ++k){
      float w = VW2[(size_t)k*HD + t];
      #pragma unroll
      for (int r = 0; r < 32; ++r) acc[r] += ag[r*128 + k] * w;
    }
    #pragma unroll
    for (int r = 0; r < 32; ++r) ob[r*128 + t] = acc[r];
  }
  __syncthreads();
  int row = t >> 2, sub = t & 3;
  float s = 0.f;
  for (int j = 0; j < 32; ++j) s += ob[row*128 + sub*32 + j];
  s += __shfl_xor(s, 1); s += __shfl_xor(s, 2);
  float mean = s * 0.0078125f;
  float v = 0.f;
  for (int j = 0; j < 32; ++j){ float d = ob[row*128 + sub*32 + j] - mean; v += d*d; }
  v += __shfl_xor(v, 1); v += __shfl_xor(v, 2);
  float rs = rsqrtf(v * 0.0078125f + 1e-5f);
  int rg = r0 + row;
  for (int j = 0; j < 32; ++j){
    int c = sub*32 + j;
    float o = (ob[row*128 + c] - mean)*rs*Vg[c] + Vbt[c];
    float nv = xv[row*128 + c] + o;
    xvf[(size_t)rg*HD + c] = nv;
    ob[row*128 + c] = nv;
  }
  __syncthreads();
  float cs = 0.f;
  #pragma unroll
  for (int r = 0; r < 32; ++r) cs += ob[r*128 + t];
  atomicAdd(&xvs[t], cs);
}

// ---------------- global-state update + next-layer bias fold ----------------
__global__ __launch_bounds__(128) void g_kernel(
    float* xvs, float* xes, float* g,
    const float* GW1, const float* Gb1, const float* GW2, const float* Gb2,
    const float* Gg, const float* Gbt,
    float* cbe, float* cbv,
    const float* EW1n, const float* Eb1n, const float* VW1n, const float* Vb1n)
{
  __shared__ float gin[384], h1[128], gn[128], red[4];
  int t = threadIdx.x;
  gin[t] = xvs[t]; gin[128 + t] = xes[t]; gin[256 + t] = g[t];
  __syncthreads();
  float a = Gb1[t];
  for (int k = 0; k < 384; ++k) a += gin[k] * GW1[(size_t)k*HD + t];
  h1[t] = fmaxf(a, 0.f);
  __syncthreads();
  float o = Gb2[t];
  for (int k = 0; k < 128; ++k) o += h1[k] * GW2[(size_t)k*HD + t];
  float s = o;
  #pragma unroll
  for (int d = 1; d < 64; d <<= 1) s += __shfl_xor(s, d);
  if ((t & 63) == 0) red[t >> 6] = s;
  __syncthreads();
  float mean = (red[0] + red[1]) * 0.0078125f;
  float dd = o - mean;
  float v = dd * dd;
  #pragma unroll
  for (int d = 1; d < 64; d <<= 1) v += __shfl_xor(v, d);
  if ((t & 63) == 0) red[2 + (t >> 6)] = v;
  __syncthreads();
  float rs = rsqrtf((red[2] + red[3]) * 0.0078125f + 1e-5f);
  float gnv = g[t] + (o - mean)*rs*Gg[t] + Gbt[t];
  g[t] = gnv; gn[t] = gnv;
  xvs[t] = 0.f; xes[t] = 0.f;
  __syncthreads();
  float ce = Eb1n[t], cv = Vb1n[t];
  for (int k = 0; k < 128; ++k){
    ce += gn[k] * EW1n[(size_t)k*HD + t];
    cv += gn[k] * VW1n[(size_t)k*HD + t];
  }
  cbe[t] = ce; cbv[t] = cv;
}

// ---------------- decoder: fp32 in, FP32 OUT ----------------
__global__ __launch_bounds__(256) void decoder_kernel(
    const float* xv, const float* c1w, const float* c1b,
    const float* c2w, const float* c2b, float* out)
{
  __shared__ float xl[4][128];
  __shared__ float hl[4][232];
  __shared__ float w1[120], b1[8], w2[80];
  __shared__ float b2s;
  int tid = threadIdx.x, nl = tid >> 6, t = tid & 63;
  int n = blockIdx.x * 4 + nl;
  if (tid < 120) w1[tid] = c1w[tid];
  else if (tid < 128) b1[tid - 120] = c1b[tid - 120];
  else if (tid < 208) w2[tid - 128] = c2w[tid - 128];
  else if (tid == 208) b2s = c2b[0];
  xl[nl][t]      = xv[(size_t)n*HD + t];
  xl[nl][t + 64] = xv[(size_t)n*HD + 64 + t];
  __syncthreads();
  for (int j = t; j < 232; j += 64){
    int ch = j / 29, pp = j % 29;
    float a = b1[ch];
    #pragma unroll
    for (int u = 0; u < 15; ++u) a += xl[nl][4*pp + u] * w1[ch*15 + u];
    hl[nl][j] = fmaxf(a, 0.f);
  }
  __syncthreads();
  if (t < 20){
    float o = b2s;
    #pragma unroll
    for (int ch = 0; ch < 8; ++ch)
      #pragma unroll
      for (int u = 0; u < 10; ++u)
        o += hl[nl][ch*29 + t + u] * w2[ch*10 + u];
    out[(size_t)n*20 + t] = o;        // FP32 output
  }
}

extern "C" void kernel_launch(void* const* d_in, const int* in_sizes, int n_in,
                              void* d_out, int out_size, void* d_ws, size_t ws_size,
                              hipStream_t stream)
{
  const float* x    = (const float*)d_in[0];
  const float* ea   = (const float*)d_in[1];
  const int*   eidx = (const int*)d_in[2];
  const float* Wn1  = (const float*)d_in[3];  const float* bn1  = (const float*)d_in[4];
  const float* Wn2  = (const float*)d_in[5];  const float* bn2  = (const float*)d_in[6];
  const float* gnln = (const float*)d_in[7];  const float* bnln = (const float*)d_in[8];
  const float* We1  = (const float*)d_in[9];  const float* be1  = (const float*)d_in[10];
  const float* We2  = (const float*)d_in[11]; const float* be2  = (const float*)d_in[12];
  const float* geln = (const float*)d_in[13]; const float* beln = (const float*)d_in[14];
  const float* lEW1 = (const float*)d_in[15]; const float* lEb1 = (const float*)d_in[16];
  const float* lEW2 = (const float*)d_in[17]; const float* lEb2 = (const float*)d_in[18];
  const float* lEg  = (const float*)d_in[19]; const float* lEbt = (const float*)d_in[20];
  const float* lVW1 = (const float*)d_in[21]; const float* lVb1 = (const float*)d_in[22];
  const float* lVW2 = (const float*)d_in[23]; const float* lVb2 = (const float*)d_in[24];
  const float* lVg  = (const float*)d_in[25]; const float* lVbt = (const float*)d_in[26];
  const float* lGW1 = (const float*)d_in[27]; const float* lGb1 = (const float*)d_in[28];
  const float* lGW2 = (const float*)d_in[29]; const float* lGb2 = (const float*)d_in[30];
  const float* lGg  = (const float*)d_in[31]; const float* lGbt = (const float*)d_in[32];
  const float* c1w  = (const float*)d_in[33]; const float* c1b  = (const float*)d_in[34];
  const float* c2w  = (const float*)d_in[35]; const float* c2b  = (const float*)d_in[36];

  char* ws = (char*)d_ws;
  size_t off = 0;
  auto alloc = [&](size_t b){ size_t o = off; off += (b + 255) & ~(size_t)255; return o; };
  float*          g    = (float*)(ws + alloc(512));
  float*          cbe  = (float*)(ws + alloc(512));
  float*          cbv  = (float*)(ws + alloc(512));
  float*          xvs  = (float*)(ws + alloc(512));
  float*          xes  = (float*)(ws + alloc(512));
  float*          xvf  = (float*)(ws + alloc((size_t)NN*HD*4));
  float*          aggr = (float*)(ws + alloc((size_t)NN*HD*4));
  unsigned short* xeb  = (unsigned short*)(ws + alloc((size_t)NE*HD*2));

  if (ws_size < off){
    sentinel_kernel<<<1, 32, 0, stream>>>((float*)d_out, 20000.f + (float)(ws_size >> 20));
    return;
  }

  init_small<<<1, 128, 0, stream>>>(g, cbe, cbv, xvs, xes, lEb1, lVb1);
  enc_node<<<NN/32, 128, 0, stream>>>(x, Wn1, bn1, Wn2, bn2, gnln, bnln, xvf);
  enc_edge<<<NE/32, 128, 0, stream>>>(ea, We1, be1, We2, be2, geln, beln, xeb);

  for (int l = 0; l < 4; ++l){
    zero_aggr<<<(NN*HD)/256, 256, 0, stream>>>(aggr);
    edge_kernel<<<NE/16, 128, 0, stream>>>(xeb, eidx, xvf, cbe,
        lEW1 + (size_t)l*512*HD, lEW2 + (size_t)l*HD*HD,
        lEb2 + (size_t)l*HD, lEg + (size_t)l*HD, lEbt + (size_t)l*HD,
        aggr, xes);
    node_kernel<<<NN/32, 128, 0, stream>>>(xvf, aggr, cbv,
        lVW1 + (size_t)l*384*HD, lVW2 + (size_t)l*HD*HD,
        lVb2 + (size_t)l*HD, lVg + (size_t)l*HD, lVbt + (size_t)l*HD,
        xvs);
    if (l < 3){
      g_kernel<<<1, 128, 0, stream>>>(xvs, xes, g,
          lGW1 + (size_t)l*384*HD, lGb1 + (size_t)l*HD,
          lGW2 + (size_t)l*HD*HD, lGb2 + (size_t)l*HD,
          lGg + (size_t)l*HD, lGbt + (size_t)l*HD,
          cbe, cbv,
          lEW1 + ((size_t)(l+1)*512 + 384)*HD, lEb1 + (size_t)(l+1)*HD,
          lVW1 + ((size_t)(l+1)*384 + 256)*HD, lVb1 + (size_t)(l+1)*HD);
    }
  }
  decoder_kernel<<<NN/4, 256, 0, stream>>>(xvf, c1w, c1b, c2w, c2b, (float*)d_out);

  hipError_t e = hipGetLastError();
  if (e != hipSuccess){
    sentinel_kernel<<<1, 32, 0, stream>>>((float*)d_out, 10000.f + (float)e);
  }
  (void)in_sizes; (void)n_in; (void)out_size;
}

// Round 11
// 1841.809 us; speedup vs baseline: 3.4407x; 3.4407x over previous
//
#include <hip/hip_runtime.h>

#define NN 20000
#define NE 160000
#define HD 128
#define SA 136   // LDS A-tile row stride (bf16 elems); 272B rows, 16B-aligned

typedef __attribute__((ext_vector_type(8))) short  bfrag;   // 8 bf16 = one MFMA A/B frag
typedef __attribute__((ext_vector_type(4))) float  facc;    // MFMA C/D frag
typedef __attribute__((ext_vector_type(4))) float  f4v;

__device__ __forceinline__ float bf2f(unsigned short u){
  union { unsigned int i; float f; } v; v.i = ((unsigned int)u) << 16; return v.f;
}
__device__ __forceinline__ unsigned short f2bf(float f){
  union { float f; unsigned int i; } v; v.f = f;
  unsigned int r = v.i + 0x7fffu + ((v.i >> 16) & 1u);
  return (unsigned short)(r >> 16);
}

__global__ void sentinel_kernel(float* out, float code){
  if (threadIdx.x < 32) out[threadIdx.x] = code;
}

// A (LDS, [64][SA] bf16) @ B (global, fragment-packed 128x128 bf16) += acc[8]
// packed[((kt*8+nt)*64+lane)*8+j] = W[kt*32+(lane>>4)*8+j][nt*16+(lane&15)]   [verified m5-m7 rounds]
__device__ __forceinline__ void gemm_tile(const short* Ab,
                                          const unsigned short* pk,
                                          int m0, int lane, facc acc[8]){
  const int q = lane >> 4, c = lane & 15;
  #pragma unroll
  for (int kt = 0; kt < 4; ++kt){
    bfrag a = *(const bfrag*)(Ab + (m0 + c) * SA + kt * 32 + q * 8);
    const bfrag* bp = (const bfrag*)pk + kt * 512 + lane;
    #pragma unroll
    for (int nt = 0; nt < 8; ++nt){
      acc[nt] = __builtin_amdgcn_mfma_f32_16x16x32_bf16(a, bp[nt * 64], acc[nt], 0, 0, 0);
    }
  }
}

// -------- pack 30 fp32 128x128 matrices -> hi/lo bf16 fragment planes (60 planes) --------
__global__ __launch_bounds__(256) void pack_all(
    const float* Wn2, const float* We2,
    const float* lEW1, const float* lEW2,
    const float* lVW1, const float* lVW2,
    unsigned short* packed)
{
  int job = blockIdx.x * 256 + threadIdx.x;   // 30 mats * 4096 (2 planes * 2048)
  int mat = job >> 12, r12 = job & 4095;
  int plane = r12 >> 11, r = r12 & 2047;
  int kt = r >> 9, nt = (r >> 6) & 7, lane = r & 63;
  const float* src;
  if (mat == 0) src = Wn2;
  else if (mat == 1) src = We2;
  else {
    int m2 = mat - 2, l = m2 / 7, t = m2 % 7;
    switch (t){
      case 0: src = lEW1 + ((size_t)l*512 +   0)*HD; break;   // P weights
      case 1: src = lEW1 + ((size_t)l*512 + 128)*HD; break;   // Q weights
      case 2: src = lEW1 + ((size_t)l*512 + 256)*HD; break;   // xe weights
      case 3: src = lEW2 + (size_t)l*HD*HD;          break;
      case 4: src = lVW1 + ((size_t)l*384 +   0)*HD; break;   // x_v weights
      case 5: src = lVW1 + ((size_t)l*384 + 128)*HD; break;   // aggr weights
      default: src = lVW2 + (size_t)l*HD*HD;         break;
    }
  }
  int krow = kt*32 + (lane>>4)*8, col = nt*16 + (lane&15);
  unsigned short v[8];
  #pragma unroll
  for (int j = 0; j < 8; ++j){
    float w = src[(size_t)(krow + j)*HD + col];
    unsigned short h = f2bf(w);
    v[j] = plane ? f2bf(w - bf2f(h)) : h;
  }
  unsigned short* dst = packed + ((size_t)mat*2 + plane)*16384
                               + ((size_t)(kt*8+nt)*64 + lane)*8;
  #pragma unroll
  for (int j = 0; j < 8; ++j) dst[j] = v[j];
}

// ---------------- init ----------------
__global__ __launch_bounds__(128) void init_small(
    float* g, float* cbe, float* cbv, float* xvs, float* xes,
    const float* Eb1_0, const float* Vb1_0)
{
  int t = threadIdx.x;
  g[t] = 0.f; xvs[t] = 0.f; xes[t] = 0.f;
  cbe[t] = Eb1_0[t]; cbv[t] = Vb1_0[t];
}

// ---------------- node encoder (MFMA MLP2): 64 rows/block ----------------
__global__ __launch_bounds__(256) void enc_node(
    const float* x, const float* W1, const float* b1,
    const unsigned short* pkW2, const float* b2,
    const float* gl, const float* bl, float* xvf, int nrows)
{
  __shared__ float inb[64*12];
  __shared__ __align__(16) short Hh[64*SA];
  __shared__ __align__(16) short Hl[64*SA];
  int tid = threadIdx.x, r0 = blockIdx.x * 64;
  for (int j = tid; j < 64*12; j += 256){
    int rr = j / 12, k = j % 12, rg = r0 + rr;
    inb[j] = (rg < nrows) ? x[(size_t)rg*12 + k] : 0.f;
  }
  __syncthreads();
  {
    int cc = tid & 127;
    float w1c[12];
    #pragma unroll
    for (int k = 0; k < 12; ++k) w1c[k] = W1[k*HD + cc];
    float bb = b1[cc];
    for (int it = 0; it < 32; ++it){
      int rr = it*2 + (tid >> 7);
      float a = bb;
      #pragma unroll
      for (int k = 0; k < 12; ++k) a += inb[rr*12 + k] * w1c[k];
      float h = fmaxf(a, 0.f);
      unsigned short hh = f2bf(h);
      Hh[rr*SA + cc] = (short)hh;
      Hl[rr*SA + cc] = (short)f2bf(h - bf2f(hh));
    }
  }
  __syncthreads();
  int lane = tid & 63, q = lane >> 4, c = lane & 15, m0 = (tid >> 6) * 16;
  facc a2[8];
  #pragma unroll
  for (int nt = 0; nt < 8; ++nt) a2[nt] = (facc){0.f,0.f,0.f,0.f};
  gemm_tile(Hh, pkW2,         m0, lane, a2);
  gemm_tile(Hl, pkW2,         m0, lane, a2);
  gemm_tile(Hh, pkW2 + 16384, m0, lane, a2);
  #pragma unroll
  for (int i = 0; i < 4; ++i){
    int rl = m0 + q*4 + i, rg = r0 + rl;
    float vals[8], s = 0.f, ss = 0.f;
    #pragma unroll
    for (int nt = 0; nt < 8; ++nt){
      float v = a2[nt][i] + b2[nt*16 + c];
      vals[nt] = v; s += v; ss += v*v;
    }
    s += __shfl_xor(s,1); ss += __shfl_xor(ss,1);
    s += __shfl_xor(s,2); ss += __shfl_xor(ss,2);
    s += __shfl_xor(s,4); ss += __shfl_xor(ss,4);
    s += __shfl_xor(s,8); ss += __shfl_xor(ss,8);
    float mean = s * 0.0078125f;
    float var  = ss * 0.0078125f - mean*mean;
    float rs   = rsqrtf(var + 1e-5f);
    if (rg < nrows){
      #pragma unroll
      for (int nt = 0; nt < 8; ++nt){
        int col = nt*16 + c;
        xvf[(size_t)rg*HD + col] = (vals[nt]-mean)*rs*gl[col] + bl[col];
      }
    }
  }
}

// ---------------- edge encoder (MFMA MLP2): 64 rows/block -> bf16 xeb ----------------
__global__ __launch_bounds__(256) void enc_edge(
    const float* ea, const float* W1, const float* b1,
    const unsigned short* pkW2, const float* b2,
    const float* gl, const float* bl, unsigned short* xeb)
{
  __shared__ float inb[64*4];
  __shared__ __align__(16) short Hh[64*SA];
  __shared__ __align__(16) short Hl[64*SA];
  int tid = threadIdx.x, r0 = blockIdx.x * 64;
  if (tid < 256){
    int rr = tid >> 2, k = tid & 3;
    inb[tid] = ea[(size_t)(r0 + rr)*4 + k];
  }
  __syncthreads();
  {
    int cc = tid & 127;
    float w0 = W1[0*HD+cc], w1 = W1[1*HD+cc], w2 = W1[2*HD+cc], w3 = W1[3*HD+cc];
    float bb = b1[cc];
    for (int it = 0; it < 32; ++it){
      int rr = it*2 + (tid >> 7);
      float a = bb + inb[rr*4+0]*w0 + inb[rr*4+1]*w1 + inb[rr*4+2]*w2 + inb[rr*4+3]*w3;
      float h = fmaxf(a, 0.f);
      unsigned short hh = f2bf(h);
      Hh[rr*SA + cc] = (short)hh;
      Hl[rr*SA + cc] = (short)f2bf(h - bf2f(hh));
    }
  }
  __syncthreads();
  int lane = tid & 63, q = lane >> 4, c = lane & 15, m0 = (tid >> 6) * 16;
  facc a2[8];
  #pragma unroll
  for (int nt = 0; nt < 8; ++nt) a2[nt] = (facc){0.f,0.f,0.f,0.f};
  gemm_tile(Hh, pkW2,         m0, lane, a2);
  gemm_tile(Hl, pkW2,         m0, lane, a2);
  gemm_tile(Hh, pkW2 + 16384, m0, lane, a2);
  #pragma unroll
  for (int i = 0; i < 4; ++i){
    int rl = m0 + q*4 + i, rg = r0 + rl;
    float vals[8], s = 0.f, ss = 0.f;
    #pragma unroll
    for (int nt = 0; nt < 8; ++nt){
      float v = a2[nt][i] + b2[nt*16 + c];
      vals[nt] = v; s += v; ss += v*v;
    }
    s += __shfl_xor(s,1); ss += __shfl_xor(ss,1);
    s += __shfl_xor(s,2); ss += __shfl_xor(ss,2);
    s += __shfl_xor(s,4); ss += __shfl_xor(ss,4);
    s += __shfl_xor(s,8); ss += __shfl_xor(ss,8);
    float mean = s * 0.0078125f;
    float var  = ss * 0.0078125f - mean*mean;
    float rs   = rsqrtf(var + 1e-5f);
    #pragma unroll
    for (int nt = 0; nt < 8; ++nt){
      int col = nt*16 + c;
      xeb[(size_t)rg*HD + col] = f2bf((vals[nt]-mean)*rs*gl[col] + bl[col]);
    }
  }
}

// ---- P,Q = x_v @ EW1[0:128], @ EW1[128:256] (bf16 out); zero this block's aggr rows ----
__global__ __launch_bounds__(256) void pq_kernel(
    const float* xvf, const unsigned short* pkA, const unsigned short* pkB,
    unsigned short* P, unsigned short* Q, float* aggr, int nrows)
{
  __shared__ __align__(16) short Ah[64*SA];
  __shared__ __align__(16) short Al[64*SA];
  int tid = threadIdx.x, r0 = blockIdx.x * 64;
  for (int j = tid; j < 1024; j += 256){
    int rr = j >> 4, ch = j & 15, rg = r0 + rr;
    float v[8];
    if (rg < nrows){
      f4v a = *(const f4v*)(xvf + (size_t)rg*HD + ch*8);
      f4v b = *(const f4v*)(xvf + (size_t)rg*HD + ch*8 + 4);
      v[0]=a[0];v[1]=a[1];v[2]=a[2];v[3]=a[3];v[4]=b[0];v[5]=b[1];v[6]=b[2];v[7]=b[3];
    } else {
      #pragma unroll
      for (int k = 0; k < 8; ++k) v[k] = 0.f;
    }
    short* dh = Ah + rr*SA + ch*8;
    short* dl = Al + rr*SA + ch*8;
    #pragma unroll
    for (int k = 0; k < 8; ++k){
      unsigned short h = f2bf(v[k]);
      dh[k] = (short)h; dl[k] = (short)f2bf(v[k] - bf2f(h));
    }
  }
  for (int j = tid; j < 2048; j += 256){
    int rr = j >> 5, ch = j & 31, rg = r0 + rr;
    if (rg < nrows) *(f4v*)(aggr + (size_t)rg*HD + ch*4) = (f4v){0.f,0.f,0.f,0.f};
  }
  __syncthreads();
  int lane = tid & 63, q = lane >> 4, c = lane & 15, m0 = (tid >> 6) * 16;
  facc ap[8], aq[8];
  #pragma unroll
  for (int nt = 0; nt < 8; ++nt){ ap[nt] = (facc){0.f,0.f,0.f,0.f}; aq[nt] = (facc){0.f,0.f,0.f,0.f}; }
  gemm_tile(Ah, pkA,         m0, lane, ap);
  gemm_tile(Al, pkA,         m0, lane, ap);
  gemm_tile(Ah, pkA + 16384, m0, lane, ap);
  gemm_tile(Ah, pkB,         m0, lane, aq);
  gemm_tile(Al, pkB,         m0, lane, aq);
  gemm_tile(Ah, pkB + 16384, m0, lane, aq);
  #pragma unroll
  for (int i = 0; i < 4; ++i){
    int rl = m0 + q*4 + i, rg = r0 + rl;
    if (rg < nrows){
      #pragma unroll
      for (int nt = 0; nt < 8; ++nt){
        int col = nt*16 + c;
        P[(size_t)rg*HD + col] = f2bf(ap[nt][i]);
        Q[(size_t)rg*HD + col] = f2bf(aq[nt][i]);
      }
    }
  }
}

// ---------------- edge update: 64 edges/block, split-precision MFMA ----------------
__global__ __launch_bounds__(256) void edge_kernel(
    unsigned short* xeb, const int* eidx,
    const unsigned short* P, const unsigned short* Q, const float* cbe,
    const unsigned short* pkW1c, const unsigned short* pkW2,
    const float* Eb2, const float* Eg, const float* Ebt,
    float* aggr, float* xe_sum)
{
  __shared__ __align__(16) short Ab[64*SA];
  __shared__ __align__(16) short Hh[64*SA];
  __shared__ __align__(16) short Hl[64*SA];
  __shared__ int sidx[64], ridx[64];
  int tid = threadIdx.x, e0 = blockIdx.x * 64;
  for (int j = tid; j < 1024; j += 256){
    int rr = j >> 4, ch = j & 15;
    *(bfrag*)(Ab + rr*SA + ch*8) = *(const bfrag*)(xeb + (size_t)(e0+rr)*HD + ch*8);
  }
  if (tid < 64){ sidx[tid] = eidx[e0+tid]; ridx[tid] = eidx[NE + e0 + tid]; }
  __syncthreads();
  int lane = tid & 63, q = lane >> 4, c = lane & 15, m0 = (tid >> 6) * 16;
  // prefetch P/Q gathers + cbe (independent of MFMA below)
  float pg[4][8];
  #pragma unroll
  for (int i = 0; i < 4; ++i){
    int rl = m0 + q*4 + i;
    const unsigned short* Ps = P + (size_t)sidx[rl]*HD;
    const unsigned short* Qr = Q + (size_t)ridx[rl]*HD;
    #pragma unroll
    for (int nt = 0; nt < 8; ++nt){
      int col = nt*16 + c;
      pg[i][nt] = bf2f(Ps[col]) + bf2f(Qr[col]) + cbe[col];
    }
  }
  facc acc[8];
  #pragma unroll
  for (int nt = 0; nt < 8; ++nt) acc[nt] = (facc){0.f,0.f,0.f,0.f};
  gemm_tile(Ab, pkW1c,         m0, lane, acc);   // xe is exact bf16 -> 2 products suffice
  gemm_tile(Ab, pkW1c + 16384, m0, lane, acc);
  #pragma unroll
  for (int i = 0; i < 4; ++i){
    int rl = m0 + q*4 + i;
    #pragma unroll
    for (int nt = 0; nt < 8; ++nt){
      int col = nt*16 + c;
      float h = fmaxf(acc[nt][i] + pg[i][nt], 0.f);
      unsigned short hh = f2bf(h);
      Hh[rl*SA + col] = (short)hh;
      Hl[rl*SA + col] = (short)f2bf(h - bf2f(hh));
    }
  }
  __syncthreads();
  facc a2[8];
  #pragma unroll
  for (int nt = 0; nt < 8; ++nt) a2[nt] = (facc){0.f,0.f,0.f,0.f};
  gemm_tile(Hh, pkW2,         m0, lane, a2);
  gemm_tile(Hl, pkW2,         m0, lane, a2);
  gemm_tile(Hh, pkW2 + 16384, m0, lane, a2);
  float csum[8] = {0.f,0.f,0.f,0.f,0.f,0.f,0.f,0.f};
  #pragma unroll
  for (int i = 0; i < 4; ++i){
    int rl = m0 + q*4 + i, eg = e0 + rl, r = ridx[rl];
    float vals[8], s = 0.f, ss = 0.f;
    #pragma unroll
    for (int nt = 0; nt < 8; ++nt){
      float v = a2[nt][i] + Eb2[nt*16 + c];
      vals[nt] = v; s += v; ss += v*v;
    }
    s += __shfl_xor(s,1); ss += __shfl_xor(ss,1);
    s += __shfl_xor(s,2); ss += __shfl_xor(ss,2);
    s += __shfl_xor(s,4); ss += __shfl_xor(ss,4);
    s += __shfl_xor(s,8); ss += __shfl_xor(ss,8);
    float mean = s * 0.0078125f;
    float var  = ss * 0.0078125f - mean*mean;
    float rs   = rsqrtf(var + 1e-5f);
    #pragma unroll
    for (int nt = 0; nt < 8; ++nt){
      int col = nt*16 + c;
      float o = (vals[nt]-mean)*rs*Eg[col] + Ebt[col];
      float nv = bf2f((unsigned short)Ab[rl*SA + col]) + o;
      unsigned short nb = f2bf(nv);
      float nvr = bf2f(nb);
      xeb[(size_t)eg*HD + col] = nb;
      atomicAdd(&aggr[(size_t)r*HD + col], nvr);
      csum[nt] += nvr;
    }
  }
  #pragma unroll
  for (int nt = 0; nt < 8; ++nt){
    float v = csum[nt]; v += __shfl_xor(v,16); v += __shfl_xor(v,32);
    if (q == 0) atomicAdd(&xe_sum[nt*16 + c], v);
  }
}

// ---------------- node update: 64 nodes/block, split-precision MFMA ----------------
__global__ __launch_bounds__(256) void node_kernel(
    float* xvf, const float* aggr, const float* cbv,
    const unsigned short* pkW1a, const unsigned short* pkW1b, const unsigned short* pkW2,
    const float* Vb2, const float* Vg, const float* Vbt,
    float* xv_sum, int nrows)
{
  __shared__ __align__(16) short Avh[64*SA];   // reused as Hh after MLP1
  __shared__ __align__(16) short Avl[64*SA];   // reused as Hl
  __shared__ __align__(16) short Agh[64*SA];
  __shared__ __align__(16) short Agl[64*SA];
  int tid = threadIdx.x, r0 = blockIdx.x * 64;
  for (int j = tid; j < 1024; j += 256){
    int rr = j >> 4, ch = j & 15, rg = r0 + rr;
    float v[8], w[8];
    if (rg < nrows){
      f4v a = *(const f4v*)(xvf  + (size_t)rg*HD + ch*8);
      f4v b = *(const f4v*)(xvf  + (size_t)rg*HD + ch*8 + 4);
      f4v e = *(const f4v*)(aggr + (size_t)rg*HD + ch*8);
      f4v f = *(const f4v*)(aggr + (size_t)rg*HD + ch*8 + 4);
      v[0]=a[0];v[1]=a[1];v[2]=a[2];v[3]=a[3];v[4]=b[0];v[5]=b[1];v[6]=b[2];v[7]=b[3];
      w[0]=e[0];w[1]=e[1];w[2]=e[2];w[3]=e[3];w[4]=f[0];w[5]=f[1];w[6]=f[2];w[7]=f[3];
    } else {
      #pragma unroll
      for (int k = 0; k < 8; ++k){ v[k]=0.f; w[k]=0.f; }
    }
    short *dvh = Avh + rr*SA + ch*8, *dvl = Avl + rr*SA + ch*8;
    short *dgh = Agh + rr*SA + ch*8, *dgl = Agl + rr*SA + ch*8;
    #pragma unroll
    for (int k = 0; k < 8; ++k){
      unsigned short h1 = f2bf(v[k]);
      dvh[k] = (short)h1; dvl[k] = (short)f2bf(v[k] - bf2f(h1));
      unsigned short h2 = f2bf(w[k]);
      dgh[k] = (short)h2; dgl[k] = (short)f2bf(w[k] - bf2f(h2));
    }
  }
  __syncthreads();
  int lane = tid & 63, q = lane >> 4, c = lane & 15, m0 = (tid >> 6) * 16;
  facc acc[8];
  #pragma unroll
  for (int nt = 0; nt < 8; ++nt) acc[nt] = (facc){0.f,0.f,0.f,0.f};
  gemm_tile(Avh, pkW1a,         m0, lane, acc);
  gemm_tile(Avl, pkW1a,         m0, lane, acc);
  gemm_tile(Avh, pkW1a + 16384, m0, lane, acc);
  gemm_tile(Agh, pkW1b,         m0, lane, acc);
  gemm_tile(Agl, pkW1b,         m0, lane, acc);
  gemm_tile(Agh, pkW1b + 16384, m0, lane, acc);
  __syncthreads();   // everyone done reading Av planes before overwrite
  #pragma unroll
  for (int i = 0; i < 4; ++i){
    int rl = m0 + q*4 + i;
    #pragma unroll
    for (int nt = 0; nt < 8; ++nt){
      int col = nt*16 + c;
      float h = fmaxf(acc[nt][i] + cbv[col], 0.f);
      unsigned short hh = f2bf(h);
      Avh[rl*SA + col] = (short)hh;          // Hh
      Avl[rl*SA + col] = (short)f2bf(h - bf2f(hh)); // Hl
    }
  }
  __syncthreads();
  facc a2[8];
  #pragma unroll
  for (int nt = 0; nt < 8; ++nt) a2[nt] = (facc){0.f,0.f,0.f,0.f};
  gemm_tile(Avh, pkW2,         m0, lane, a2);
  gemm_tile(Avl, pkW2,         m0, lane, a2);
  gemm_tile(Avh, pkW2 + 16384, m0, lane, a2);
  float csum[8] = {0.f,0.f,0.f,0.f,0.f,0.f,0.f,0.f};
  #pragma unroll
  for (int i = 0; i < 4; ++i){
    int rl = m0 + q*4 + i, rg = r0 + rl;
    bool ok = rg < nrows;
    float vals[8], s = 0.f, ss = 0.f;
    #pragma unroll
    for (int nt = 0; nt < 8; ++nt){
      float v = a2[nt][i] + Vb2[nt*16 + c];
      vals[nt] = v; s += v; ss += v*v;
    }
    s += __shfl_xor(s,1); ss += __shfl_xor(ss,1);
    s += __shfl_xor(s,2); ss += __shfl_xor(ss,2);
    s += __shfl_xor(s,4); ss += __shfl_xor(ss,4);
    s += __shfl_xor(s,8); ss += __shfl_xor(ss,8);
    float mean = s * 0.0078125f;
    float var  = ss * 0.0078125f - mean*mean;
    float rs   = rsqrtf(var + 1e-5f);
    if (ok){
      #pragma unroll
      for (int nt = 0; nt < 8; ++nt){
        int col = nt*16 + c;
        float o = (vals[nt]-mean)*rs*Vg[col] + Vbt[col];
        size_t gi = (size_t)rg*HD + col;
        float nv = xvf[gi] + o;
        xvf[gi] = nv;
        csum[nt] += nv;
      }
    }
  }
  #pragma unroll
  for (int nt = 0; nt < 8; ++nt){
    float v = csum[nt]; v += __shfl_xor(v,16); v += __shfl_xor(v,32);
    if (q == 0) atomicAdd(&xv_sum[nt*16 + c], v);
  }
}

// ---------------- global-state update + next-layer bias fold (fp32) ----------------
__global__ __launch_bounds__(128) void g_kernel(
    float* xvs, float* xes, float* g,
    const float* GW1, const float* Gb1, const float* GW2, const float* Gb2,
    const float* Gg, const float* Gbt,
    float* cbe, float* cbv,
    const float* EW1n, const float* Eb1n, const float* VW1n, const float* Vb1n)
{
  __shared__ float gin[384], h1[128], gn[128], red[4];
  int t = threadIdx.x;
  gin[t] = xvs[t]; gin[128 + t] = xes[t]; gin[256 + t] = g[t];
  __syncthreads();
  float a = Gb1[t];
  for (int k = 0; k < 384; ++k) a += gin[k] * GW1[(size_t)k*HD + t];
  h1[t] = fmaxf(a, 0.f);
  __syncthreads();
  float o = Gb2[t];
  for (int k = 0; k < 128; ++k) o += h1[k] * GW2[(size_t)k*HD + t];
  float s = o;
  #pragma unroll
  for (int d = 1; d < 64; d <<= 1) s += __shfl_xor(s, d);
  if ((t & 63) == 0) red[t >> 6] = s;
  __syncthreads();
  float mean = (red[0] + red[1]) * 0.0078125f;
  float dd = o - mean;
  float v = dd * dd;
  #pragma unroll
  for (int d = 1; d < 64; d <<= 1) v += __shfl_xor(v, d);
  if ((t & 63) == 0) red[2 + (t >> 6)] = v;
  __syncthreads();
  float rs = rsqrtf((red[2] + red[3]) * 0.0078125f + 1e-5f);
  float gnv = g[t] + (o - mean)*rs*Gg[t] + Gbt[t];
  g[t] = gnv; gn[t] = gnv;
  xvs[t] = 0.f; xes[t] = 0.f;
  __syncthreads();
  float ce = Eb1n[t], cv = Vb1n[t];
  for (int k = 0; k < 128; ++k){
    ce += gn[k] * EW1n[(size_t)k*HD + t];
    cv += gn[k] * VW1n[(size_t)k*HD + t];
  }
  cbe[t] = ce; cbv[t] = cv;
}

// ---------------- decoder: fp32 in, fp32 out ----------------
__global__ __launch_bounds__(256) void decoder_kernel(
    const float* xv, const float* c1w, const float* c1b,
    const float* c2w, const float* c2b, float* out)
{
  __shared__ float xl[4][128];
  __shared__ float hl[4][232];
  __shared__ float w1[120], b1[8], w2[80];
  __shared__ float b2s;
  int tid = threadIdx.x, nl = tid >> 6, t = tid & 63;
  int n = blockIdx.x * 4 + nl;
  if (tid < 120) w1[tid] = c1w[tid];
  else if (tid < 128) b1[tid - 120] = c1b[tid - 120];
  else if (tid < 208) w2[tid - 128] = c2w[tid - 128];
  else if (tid == 208) b2s = c2b[0];
  xl[nl][t]      = xv[(size_t)n*HD + t];
  xl[nl][t + 64] = xv[(size_t)n*HD + 64 + t];
  __syncthreads();
  for (int j = t; j < 232; j += 64){
    int ch = j / 29, pp = j % 29;
    float a = b1[ch];
    #pragma unroll
    for (int u = 0; u < 15; ++u) a += xl[nl][4*pp + u] * w1[ch*15 + u];
    hl[nl][j] = fmaxf(a, 0.f);
  }
  __syncthreads();
  if (t < 20){
    float o = b2s;
    #pragma unroll
    for (int ch = 0; ch < 8; ++ch)
      #pragma unroll
      for (int u = 0; u < 10; ++u)
        o += hl[nl][ch*29 + t + u] * w2[ch*10 + u];
    out[(size_t)n*20 + t] = o;
  }
}

extern "C" void kernel_launch(void* const* d_in, const int* in_sizes, int n_in,
                              void* d_out, int out_size, void* d_ws, size_t ws_size,
                              hipStream_t stream)
{
  const float* x    = (const float*)d_in[0];
  const float* ea   = (const float*)d_in[1];
  const int*   eidx = (const int*)d_in[2];
  const float* Wn1  = (const float*)d_in[3];  const float* bn1  = (const float*)d_in[4];
  const float* Wn2  = (const float*)d_in[5];  const float* bn2  = (const float*)d_in[6];
  const float* gnln = (const float*)d_in[7];  const float* bnln = (const float*)d_in[8];
  const float* We1  = (const float*)d_in[9];  const float* be1  = (const float*)d_in[10];
  const float* We2  = (const float*)d_in[11]; const float* be2  = (const float*)d_in[12];
  const float* geln = (const float*)d_in[13]; const float* beln = (const float*)d_in[14];
  const float* lEW1 = (const float*)d_in[15]; const float* lEb1 = (const float*)d_in[16];
  const float* lEW2 = (const float*)d_in[17]; const float* lEb2 = (const float*)d_in[18];
  const float* lEg  = (const float*)d_in[19]; const float* lEbt = (const float*)d_in[20];
  const float* lVW1 = (const float*)d_in[21]; const float* lVb1 = (const float*)d_in[22];
  const float* lVW2 = (const float*)d_in[23]; const float* lVb2 = (const float*)d_in[24];
  const float* lVg  = (const float*)d_in[25]; const float* lVbt = (const float*)d_in[26];
  const float* lGW1 = (const float*)d_in[27]; const float* lGb1 = (const float*)d_in[28];
  const float* lGW2 = (const float*)d_in[29]; const float* lGb2 = (const float*)d_in[30];
  const float* lGg  = (const float*)d_in[31]; const float* lGbt = (const float*)d_in[32];
  const float* c1w  = (const float*)d_in[33]; const float* c1b  = (const float*)d_in[34];
  const float* c2w  = (const float*)d_in[35]; const float* c2b  = (const float*)d_in[36];

  char* ws = (char*)d_ws;
  size_t off = 0;
  auto alloc = [&](size_t b){ size_t o = off; off += (b + 255) & ~(size_t)255; return o; };
  unsigned short* pk   = (unsigned short*)(ws + alloc((size_t)30*2*16384*2)); // 1.97 MB hi/lo planes
  float*          g    = (float*)(ws + alloc(512));
  float*          cbe  = (float*)(ws + alloc(512));
  float*          cbv  = (float*)(ws + alloc(512));
  float*          xvs  = (float*)(ws + alloc(512));
  float*          xes  = (float*)(ws + alloc(512));
  float*          xvf  = (float*)(ws + alloc((size_t)NN*HD*4));          // 10.24 MB
  unsigned short* P    = (unsigned short*)(ws + alloc((size_t)NN*HD*2)); //  5.12 MB
  unsigned short* Q    = (unsigned short*)(ws + alloc((size_t)NN*HD*2)); //  5.12 MB
  float*          aggr = (float*)(ws + alloc((size_t)NN*HD*4));          // 10.24 MB
  unsigned short* xeb  = (unsigned short*)(ws + alloc((size_t)NE*HD*2)); // 40.96 MB

  if (ws_size < off){
    sentinel_kernel<<<1, 32, 0, stream>>>((float*)d_out, 20000.f + (float)(ws_size >> 20));
    return;
  }

  auto slot = [&](int m){ return pk + (size_t)m * 32768; };  // hi at +0, lo at +16384

  pack_all<<<480, 256, 0, stream>>>(Wn2, We2, lEW1, lEW2, lVW1, lVW2, pk);
  init_small<<<1, 128, 0, stream>>>(g, cbe, cbv, xvs, xes, lEb1, lVb1);
  enc_node<<<(NN + 63)/64, 256, 0, stream>>>(x, Wn1, bn1, slot(0), bn2, gnln, bnln, xvf, NN);
  enc_edge<<<NE/64, 256, 0, stream>>>(ea, We1, be1, slot(1), be2, geln, beln, xeb);

  for (int l = 0; l < 4; ++l){
    int m = 2 + 7*l;
    pq_kernel<<<(NN + 63)/64, 256, 0, stream>>>(xvf, slot(m+0), slot(m+1), P, Q, aggr, NN);
    edge_kernel<<<NE/64, 256, 0, stream>>>(xeb, eidx, P, Q, cbe,
        slot(m+2), slot(m+3),
        lEb2 + (size_t)l*HD, lEg + (size_t)l*HD, lEbt + (size_t)l*HD,
        aggr, xes);
    node_kernel<<<(NN + 63)/64, 256, 0, stream>>>(xvf, aggr, cbv,
        slot(m+4), slot(m+5), slot(m+6),
        lVb2 + (size_t)l*HD, lVg + (size_t)l*HD, lVbt + (size_t)l*HD,
        xvs, NN);
    if (l < 3){
      g_kernel<<<1, 128, 0, stream>>>(xvs, xes, g,
          lGW1 + (size_t)l*384*HD, lGb1 + (size_t)l*HD,
          lGW2 + (size_t)l*HD*HD, lGb2 + (size_t)l*HD,
          lGg + (size_t)l*HD, lGbt + (size_t)l*HD,
          cbe, cbv,
          lEW1 + ((size_t)(l+1)*512 + 384)*HD, lEb1 + (size_t)(l+1)*HD,
          lVW1 + ((size_t)(l+1)*384 + 256)*HD, lVb1 + (size_t)(l+1)*HD);
    }
  }
  decoder_kernel<<<NN/4, 256, 0, stream>>>(xvf, c1w, c1b, c2w, c2b, (float*)d_out);

  hipError_t e = hipGetLastError();
  if (e != hipSuccess){
    sentinel_kernel<<<1, 32, 0, stream>>>((float*)d_out, 10000.f + (float)e);
  }
  (void)in_sizes; (void)n_in; (void)out_size;
}